// Round 1
// baseline (217.402 us; speedup 1.0000x reference)
//
#include <hip/hip_runtime.h>

// Voigt index pairs (11,22,33,12,13,23)
static constexpr int VII[6] = {0, 1, 2, 0, 0, 1};
static constexpr int VJJ[6] = {0, 1, 2, 1, 2, 2};

// Outputs (concatenated flat, fp32):
//   psi     : [0, N)
//   Cauchy6 : [N, 7N)       (N,6) row-major
//   DDSDDE  : [7N, 43N)     (N,6,6) row-major
template <bool VEC>
__global__ __launch_bounds__(256) void nh3d_kernel(
    const float* __restrict__ Fg, const float* __restrict__ mp,
    float* __restrict__ out, int N)
{
    const int idx = blockIdx.x * blockDim.x + threadIdx.x;
    if (idx >= N) return;

    const float c1 = mp[0];
    const float c2 = mp[1];

    float F[3][3];
    {
        const float* fp = Fg + (size_t)idx * 9;
#pragma unroll
        for (int r = 0; r < 3; ++r)
#pragma unroll
            for (int c = 0; c < 3; ++c)
                F[r][c] = fp[3 * r + c];
    }

    // J = det(F)
    const float J = F[0][0] * (F[1][1] * F[2][2] - F[1][2] * F[2][1])
                  - F[0][1] * (F[1][0] * F[2][2] - F[1][2] * F[2][0])
                  + F[0][2] * (F[1][0] * F[2][1] - F[1][1] * F[2][0]);

    // b = F F^T (symmetric)
    float b[3][3];
#pragma unroll
    for (int r = 0; r < 3; ++r)
#pragma unroll
        for (int c = 0; c < 3; ++c) {
            if (c > r) continue;
            const float s = F[r][0] * F[c][0] + F[r][1] * F[c][1] + F[r][2] * F[c][2];
            b[r][c] = s;
            b[c][r] = s;
        }

    const float I1   = b[0][0] + b[1][1] + b[2][2];
    const float invJ = 1.0f / J;
    const float Jm23 = cbrtf(invJ * invJ);   // J^(-2/3)

    // psi
    const float psi = c1 * (Jm23 * I1 - 3.0f) + c2 * (J - 1.0f) * (J - 1.0f);

    // Kirchhoff tau = 2 c1 J^{-2/3} (b - (I1/3) I) + 2 c2 (J-1) J I   (symmetric)
    const float c1t  = 2.0f * c1 * Jm23;
    const float diag = 2.0f * c2 * (J - 1.0f) * J - c1t * (I1 * (1.0f / 3.0f));
    float tau[3][3];
#pragma unroll
    for (int r = 0; r < 3; ++r)
#pragma unroll
        for (int c = 0; c < 3; ++c)
            tau[r][c] = c1t * b[r][c] + (r == c ? diag : 0.0f);

    // Cauchy (Voigt) = tau / J
    float cau[6];
#pragma unroll
    for (int a = 0; a < 6; ++a)
        cau[a] = tau[VII[a]][VJJ[a]] * invJ;

    // Tangent coefficients
    const float gE  = 2.0f * c2 * (2.0f * J - 1.0f) * J;  // * δij δkl (volumetric)
    const float gF  = -2.0f * c2 * (J - 1.0f) * J;        // * δil δjk (volumetric)
    const float cA  = c1t * (2.0f * I1 * (1.0f / 9.0f));  // * δij δkl (isochoric)
    const float cB  = c1t * (I1 * (1.0f / 3.0f));         // * δil δjk (isochoric)
    const float m23 = -(2.0f / 3.0f) * c1t;

    float dd[36];
#pragma unroll
    for (int a = 0; a < 6; ++a) {
        const int i = VII[a], j = VJJ[a];
#pragma unroll
        for (int q = 0; q < 6; ++q) {
            const int k = VII[q], l = VJJ[q];
            float s = 0.0f;
            if (i == k) s += c1t * b[j][l];
            if (k == l) s += m23 * b[i][j];
            if (i == j) s += m23 * b[k][l];
            if (i == j && k == l) s += cA + gE;
            if (i == l && j == k) s += cB + gF;
            // geometric correction: 0.5*(tau_ik δjl + tau_il δjk + tau_jk δil - tau_jl δik)
            float g = 0.0f;
            if (j == l) g += tau[i][k];
            if (j == k) g += tau[i][l];
            if (i == l) g += tau[j][k];
            if (i == k) g -= tau[j][l];
            dd[6 * a + q] = (s + 0.5f * g) * invJ;
        }
    }

    // Stores
    out[idx] = psi;
    float* cout_ = out + (size_t)N + (size_t)idx * 6;
    float* dout_ = out + (size_t)7 * N + (size_t)idx * 36;
    if (VEC) {
#pragma unroll
        for (int v = 0; v < 3; ++v)
            *reinterpret_cast<float2*>(cout_ + 2 * v) =
                make_float2(cau[2 * v], cau[2 * v + 1]);
#pragma unroll
        for (int v = 0; v < 9; ++v)
            *reinterpret_cast<float4*>(dout_ + 4 * v) =
                make_float4(dd[4 * v], dd[4 * v + 1], dd[4 * v + 2], dd[4 * v + 3]);
    } else {
#pragma unroll
        for (int a = 0; a < 6; ++a) cout_[a] = cau[a];
#pragma unroll
        for (int a = 0; a < 36; ++a) dout_[a] = dd[a];
    }
}

extern "C" void kernel_launch(void* const* d_in, const int* in_sizes, int n_in,
                              void* d_out, int out_size, void* d_ws, size_t ws_size,
                              hipStream_t stream) {
    const int N = in_sizes[0] / 9;
    const float* F_in    = (const float*)d_in[0];
    const float* mat_par = (const float*)d_in[1];
    float* out = (float*)d_out;

    const int block = 256;
    const int grid  = (N + block - 1) / block;

    // float4 path needs (7N) % 4 == 0 and (N) % 2 == 0 for aligned vector stores
    if (N % 4 == 0) {
        nh3d_kernel<true><<<grid, block, 0, stream>>>(F_in, mat_par, out, N);
    } else {
        nh3d_kernel<false><<<grid, block, 0, stream>>>(F_in, mat_par, out, N);
    }
}

// Round 2
// 193.951 us; speedup vs baseline: 1.1209x; 1.1209x over previous
//
#include <hip/hip_runtime.h>

// Voigt index pairs (11,22,33,12,13,23)
static constexpr int VII[6] = {0, 1, 2, 0, 0, 1};
static constexpr int VJJ[6] = {0, 1, 2, 1, 2, 2};

// Closed-form Neo-Hookean point evaluation (verified round 1, absmax 1.6e-2).
__device__ __forceinline__ void nh_compute(const float F[3][3], float c1, float c2,
                                           float& psi, float cau[6], float dd[36])
{
    // J = det(F)
    const float J = F[0][0] * (F[1][1] * F[2][2] - F[1][2] * F[2][1])
                  - F[0][1] * (F[1][0] * F[2][2] - F[1][2] * F[2][0])
                  + F[0][2] * (F[1][0] * F[2][1] - F[1][1] * F[2][0]);

    // b = F F^T (symmetric)
    float b[3][3];
#pragma unroll
    for (int r = 0; r < 3; ++r)
#pragma unroll
        for (int c = 0; c < 3; ++c) {
            if (c > r) continue;
            const float s = F[r][0] * F[c][0] + F[r][1] * F[c][1] + F[r][2] * F[c][2];
            b[r][c] = s;
            b[c][r] = s;
        }

    const float I1   = b[0][0] + b[1][1] + b[2][2];
    const float invJ = 1.0f / J;
    const float Jm23 = cbrtf(invJ * invJ);   // J^(-2/3)

    psi = c1 * (Jm23 * I1 - 3.0f) + c2 * (J - 1.0f) * (J - 1.0f);

    // Kirchhoff tau = 2 c1 J^{-2/3} (b - (I1/3) I) + 2 c2 (J-1) J I
    const float c1t  = 2.0f * c1 * Jm23;
    const float diag = 2.0f * c2 * (J - 1.0f) * J - c1t * (I1 * (1.0f / 3.0f));
    float tau[3][3];
#pragma unroll
    for (int r = 0; r < 3; ++r)
#pragma unroll
        for (int c = 0; c < 3; ++c)
            tau[r][c] = c1t * b[r][c] + (r == c ? diag : 0.0f);

#pragma unroll
    for (int a = 0; a < 6; ++a)
        cau[a] = tau[VII[a]][VJJ[a]] * invJ;

    const float gE  = 2.0f * c2 * (2.0f * J - 1.0f) * J;
    const float gF  = -2.0f * c2 * (J - 1.0f) * J;
    const float cA  = c1t * (2.0f * I1 * (1.0f / 9.0f));
    const float cB  = c1t * (I1 * (1.0f / 3.0f));
    const float m23 = -(2.0f / 3.0f) * c1t;

#pragma unroll
    for (int a = 0; a < 6; ++a) {
        const int i = VII[a], j = VJJ[a];
#pragma unroll
        for (int q = 0; q < 6; ++q) {
            const int k = VII[q], l = VJJ[q];
            float s = 0.0f;
            if (i == k) s += c1t * b[j][l];
            if (k == l) s += m23 * b[i][j];
            if (i == j) s += m23 * b[k][l];
            if (i == j && k == l) s += cA + gE;
            if (i == l && j == k) s += cB + gF;
            float g = 0.0f;
            if (j == l) g += tau[i][k];
            if (j == k) g += tau[i][l];
            if (i == l) g += tau[j][k];
            if (i == k) g -= tau[j][l];
            dd[6 * a + q] = (s + 0.5f * g) * invJ;
        }
    }
}

// ---------------------------------------------------------------------------
// Main kernel: wave-private LDS staging -> fully dense stores.
// Requires N % 4 == 0 (16B-aligned float4 store bases). Covers points
// [0, 64*nWaves); tail handled by nh3d_scatter.
// ---------------------------------------------------------------------------
#define WPB 4           // waves per block
#define DPAD 37         // 36 + 1 (odd stride -> conflict-free LDS writes)

__global__ __launch_bounds__(256) void nh3d_coal(
    const float* __restrict__ Fg, const float* __restrict__ mp,
    float* __restrict__ out, int N, int nWaves)
{
    __shared__ float sbuf[WPB][64 * DPAD];

    const int tid  = threadIdx.x;
    const int wave = tid >> 6;
    const int lane = tid & 63;
    const int waveIdx = blockIdx.x * WPB + wave;
    if (waveIdx >= nWaves) return;
    const int waveStart = waveIdx * 64;
    const int idx = waveStart + lane;

    const float c1 = mp[0];
    const float c2 = mp[1];

    float F[3][3];
    {
        const float* fp = Fg + (size_t)idx * 9;
#pragma unroll
        for (int r = 0; r < 3; ++r)
#pragma unroll
            for (int c = 0; c < 3; ++c)
                F[r][c] = fp[3 * r + c];
    }

    float psi, cau[6], dd[36];
    nh_compute(F, c1, c2, psi, cau, dd);

    // psi: already dense across lanes
    out[idx] = psi;

    float* sw = sbuf[wave];

    // ---- DDSDDE: stage record to LDS, store dense -------------------------
#pragma unroll
    for (int j = 0; j < 36; ++j)
        sw[lane * DPAD + j] = dd[j];
    // wave-private buffer: in-order DS pipe makes RAW safe without barrier

    float* dout = out + (size_t)7 * N + (size_t)waveStart * 36;
#pragma unroll
    for (int k = 0; k < 9; ++k) {
        const int g = k * 256 + lane * 4;     // g % 4 == 0 -> never crosses a record
        const int p = g / 36;                 // magic-mul
        const int base = p * DPAD + (g - p * 36);  // = g + p
        const float4 v = make_float4(sw[base], sw[base + 1], sw[base + 2], sw[base + 3]);
        *reinterpret_cast<float4*>(dout + g) = v;
    }

    // ---- Cauchy6: same trick (reuse buffer; WAR safe in-order) ------------
#pragma unroll
    for (int j = 0; j < 6; ++j)
        sw[lane * 7 + j] = cau[j];

    float* cout_ = out + (size_t)N + (size_t)waveStart * 6;
#pragma unroll
    for (int k = 0; k < 3; ++k) {
        const int g = k * 128 + lane * 2;     // g % 2 == 0 -> never crosses a record
        const int p = g / 6;
        const int base = p * 7 + (g - p * 6); // = g + p
        *reinterpret_cast<float2*>(cout_ + g) = make_float2(sw[base], sw[base + 1]);
    }
}

// ---------------------------------------------------------------------------
// Fallback / tail: scalar scattered stores (correct for any N).
// ---------------------------------------------------------------------------
__global__ __launch_bounds__(256) void nh3d_scatter(
    const float* __restrict__ Fg, const float* __restrict__ mp,
    float* __restrict__ out, int N, int start)
{
    const int idx = start + blockIdx.x * blockDim.x + threadIdx.x;
    if (idx >= N) return;

    const float c1 = mp[0];
    const float c2 = mp[1];

    float F[3][3];
    {
        const float* fp = Fg + (size_t)idx * 9;
#pragma unroll
        for (int r = 0; r < 3; ++r)
#pragma unroll
            for (int c = 0; c < 3; ++c)
                F[r][c] = fp[3 * r + c];
    }

    float psi, cau[6], dd[36];
    nh_compute(F, c1, c2, psi, cau, dd);

    out[idx] = psi;
    float* cout_ = out + (size_t)N + (size_t)idx * 6;
    float* dout  = out + (size_t)7 * N + (size_t)idx * 36;
#pragma unroll
    for (int a = 0; a < 6; ++a) cout_[a] = cau[a];
#pragma unroll
    for (int a = 0; a < 36; ++a) dout[a] = dd[a];
}

extern "C" void kernel_launch(void* const* d_in, const int* in_sizes, int n_in,
                              void* d_out, int out_size, void* d_ws, size_t ws_size,
                              hipStream_t stream) {
    const int N = in_sizes[0] / 9;
    const float* F_in    = (const float*)d_in[0];
    const float* mat_par = (const float*)d_in[1];
    float* out = (float*)d_out;

    if (N >= 64 && (N % 4) == 0) {
        const int nWaves = N / 64;
        const int grid = (nWaves + WPB - 1) / WPB;
        nh3d_coal<<<grid, 256, 0, stream>>>(F_in, mat_par, out, N, nWaves);
        const int tail = N - nWaves * 64;
        if (tail > 0) {
            nh3d_scatter<<<1, 64, 0, stream>>>(F_in, mat_par, out, N, nWaves * 64);
        }
    } else {
        const int grid = (N + 255) / 256;
        nh3d_scatter<<<grid, 256, 0, stream>>>(F_in, mat_par, out, N, 0);
    }
}